// Round 12
// baseline (1433.814 us; speedup 1.0000x reference)
//
#include <hip/hip_runtime.h>

#define V_  32000
#define C_  1024
#define T_  1024
#define H_  16
#define L_  4
#define B_  4
#define HD_ 64
#define FF_ 4096
#define M_  (B_ * T_)   // 4096 token rows

typedef __attribute__((ext_vector_type(8))) short bf16x8;
typedef __attribute__((ext_vector_type(4))) float f32x4;
typedef unsigned short u16;

#define FENCE() asm volatile("" ::: "memory")
#define BAR()  do { FENCE(); __builtin_amdgcn_s_barrier(); FENCE(); } while (0)
#define VMW(n) asm volatile("s_waitcnt vmcnt(" #n ")" ::: "memory")

__device__ __forceinline__ u16 f2bf(float f) {
  unsigned u = __builtin_bit_cast(unsigned, f);
  u += 0x7fffu + ((u >> 16) & 1u);        // round-to-nearest-even
  return (u16)(u >> 16);
}

__device__ __forceinline__ float gelu_f(float v) {
  return 0.5f * v * (1.0f + erff(v * 0.70710678118654752f));
}

__device__ __forceinline__ void gload16(const u16* g, u16* l) {
  __builtin_amdgcn_global_load_lds(
      (const __attribute__((address_space(1))) void*)g,
      (__attribute__((address_space(3))) void*)l, 16, 0, 0);
}

// ---------------------------------------------------------------- embedding (+ optional fused LN)
template <int FUSE_LN>
__global__ __launch_bounds__(256)
void embed_kernel(const int* __restrict__ idx, const float* __restrict__ emb,
                  const float* __restrict__ pos, float* __restrict__ x,
                  const float* __restrict__ g, const float* __restrict__ bta,
                  u16* __restrict__ hout) {
  int row = blockIdx.x;
  int t = row & (T_ - 1);
  int tok = idx[row];
  float4 e = reinterpret_cast<const float4*>(emb + (size_t)tok * C_)[threadIdx.x];
  float4 p = reinterpret_cast<const float4*>(pos + (size_t)t * C_)[threadIdx.x];
  float4 r;
  r.x = e.x + p.x; r.y = e.y + p.y; r.z = e.z + p.z; r.w = e.w + p.w;
  reinterpret_cast<float4*>(x + (size_t)row * C_)[threadIdx.x] = r;
  if constexpr (FUSE_LN) {
    int tid = threadIdx.x;
    float s  = r.x + r.y + r.z + r.w;
    float ss = r.x * r.x + r.y * r.y + r.z * r.z + r.w * r.w;
    #pragma unroll
    for (int d = 1; d < 64; d <<= 1) {
      s  += __shfl_xor(s, d, 64);
      ss += __shfl_xor(ss, d, 64);
    }
    __shared__ float rs[4], rss[4];
    int w = tid >> 6, lane = tid & 63;
    if (lane == 0) { rs[w] = s; rss[w] = ss; }
    __syncthreads();
    s  = rs[0] + rs[1] + rs[2] + rs[3];
    ss = rss[0] + rss[1] + rss[2] + rss[3];
    float mean = s * (1.0f / C_);
    float var  = ss * (1.0f / C_) - mean * mean;
    float rstd = rsqrtf(var + 1e-5f);
    float4 gv = reinterpret_cast<const float4*>(g)[tid];
    float4 bv = reinterpret_cast<const float4*>(bta)[tid];
    union { u16 u[4]; uint2 v; } pk;
    pk.u[0] = f2bf((r.x - mean) * rstd * gv.x + bv.x);
    pk.u[1] = f2bf((r.y - mean) * rstd * gv.y + bv.y);
    pk.u[2] = f2bf((r.z - mean) * rstd * gv.z + bv.z);
    pk.u[3] = f2bf((r.w - mean) * rstd * gv.w + bv.w);
    *reinterpret_cast<uint2*>(&hout[(size_t)row * C_ + tid * 4]) = pk.v;
  }
}

// ---------------------------------------------------------------- layernorm (1 wave / row)
__global__ __launch_bounds__(256)
void ln_kernel(const float* __restrict__ xin, const float* __restrict__ g,
               const float* __restrict__ bta, u16* __restrict__ out) {
  const int w = threadIdx.x >> 6, lane = threadIdx.x & 63;
  const int row = blockIdx.x * 4 + w;
  const float4* xr = reinterpret_cast<const float4*>(xin + (size_t)row * C_);
  float4 xv[4];
  float s = 0.f, ss = 0.f;
  #pragma unroll
  for (int j = 0; j < 4; ++j) {
    xv[j] = xr[lane + 64 * j];
    s  += xv[j].x + xv[j].y + xv[j].z + xv[j].w;
    ss += xv[j].x * xv[j].x + xv[j].y * xv[j].y + xv[j].z * xv[j].z + xv[j].w * xv[j].w;
  }
  #pragma unroll
  for (int d = 1; d < 64; d <<= 1) {
    s  += __shfl_xor(s, d, 64);
    ss += __shfl_xor(ss, d, 64);
  }
  float mean = s * (1.0f / C_);
  float var  = ss * (1.0f / C_) - mean * mean;
  float rstd = rsqrtf(var + 1e-5f);
  #pragma unroll
  for (int j = 0; j < 4; ++j) {
    float4 gv = reinterpret_cast<const float4*>(g)[lane + 64 * j];
    float4 bv = reinterpret_cast<const float4*>(bta)[lane + 64 * j];
    union { u16 u[4]; uint2 v; } pk;
    pk.u[0] = f2bf((xv[j].x - mean) * rstd * gv.x + bv.x);
    pk.u[1] = f2bf((xv[j].y - mean) * rstd * gv.y + bv.y);
    pk.u[2] = f2bf((xv[j].z - mean) * rstd * gv.z + bv.z);
    pk.u[3] = f2bf((xv[j].w - mean) * rstd * gv.w + bv.w);
    *reinterpret_cast<uint2*>(&out[(size_t)row * C_ + (lane + 64 * j) * 4]) = pk.v;
  }
}

// ---------------------------------------------------------------- weight transpose+convert (generic)
__global__ __launch_bounds__(256)
void wtrans_kernel(const float* __restrict__ W, u16* __restrict__ Wt, int K, int N,
                   size_t dstBS) {
  const float* src = W + (size_t)blockIdx.z * K * N;
  u16* dst = Wt + (size_t)blockIdx.z * dstBS;
  __shared__ float tile[32][33];
  int k0 = blockIdx.y * 32, n0 = blockIdx.x * 32;
  int tx = threadIdx.x & 31, ty = threadIdx.x >> 5;
  #pragma unroll
  for (int i = 0; i < 4; ++i)
    tile[ty * 4 + i][tx] = src[(size_t)(k0 + ty * 4 + i) * N + n0 + tx];
  __syncthreads();
  int n = threadIdx.x >> 3, q = threadIdx.x & 7;
  union { u16 u[4]; uint2 v; } pk;
  #pragma unroll
  for (int j = 0; j < 4; ++j) pk.u[j] = f2bf(tile[4 * q + j][n]);
  *reinterpret_cast<uint2*>(&dst[(size_t)(n0 + n) * K + k0 + 4 * q]) = pk.v;
}

// merged C_xC_ transpose: z = 16 slices (layer = z&3, which = z>>2: q,k,v,o)
__global__ __launch_bounds__(256)
void wtrans4_kernel(const float* __restrict__ Wq, const float* __restrict__ Wk,
                    const float* __restrict__ Wv, const float* __restrict__ Wo,
                    u16* __restrict__ WqkvT, u16* __restrict__ WoT) {
  int zz = blockIdx.z;
  int l = zz & 3, which = zz >> 2;
  const float* src = (which == 0 ? Wq : which == 1 ? Wk : which == 2 ? Wv : Wo)
                     + (size_t)l * C_ * C_;
  u16* dst = (which == 3)
      ? WoT + (size_t)l * C_ * C_
      : WqkvT + (size_t)l * 3 * C_ * C_ + (size_t)which * C_ * C_;
  __shared__ float tile[32][33];
  int k0 = blockIdx.y * 32, n0 = blockIdx.x * 32;
  int tx = threadIdx.x & 31, ty = threadIdx.x >> 5;
  #pragma unroll
  for (int i = 0; i < 4; ++i)
    tile[ty * 4 + i][tx] = src[(size_t)(k0 + ty * 4 + i) * C_ + n0 + tx];
  __syncthreads();
  int n = threadIdx.x >> 3, q = threadIdx.x & 7;
  union { u16 u[4]; uint2 v; } pk;
  #pragma unroll
  for (int j = 0; j < 4; ++j) pk.u[j] = f2bf(tile[4 * q + j][n]);
  *reinterpret_cast<uint2*>(&dst[(size_t)(n0 + n) * C_ + k0 + 4 * q]) = pk.v;
}

// ---------------------------------------------------------------- GEMM 128x128, 3-deep pipelined
// (T4 counted vmcnt: 3 LDS buffer sets; tile t's loads get ~2 iterations to
// land, VMW(8) in steady state — latency hidden even at 1 wave/SIMD.)
// MODE 1: fp32 = acc + bias + residual (Wo, W2) -- LDS-transpose epilogue
// MODE 2: bf16 = gelu(acc + bias)      (W1)     -- LDS-staged coalesced stores
// MODE 3: fp32 = acc + bias            (LM)     -- direct stores (proven best)
// MODE 4: QKV fused: Q/K -> bf16 stride 2C (LDS-staged); V -> vtb[b][h][d][t]
template <int MODE, int GROUP_M>
__global__ __launch_bounds__(256)
void gemm_bt(const u16* __restrict__ A, const u16* __restrict__ Bt,
             const float* __restrict__ bias, const float* __restrict__ resid,
             void* __restrict__ Cout, u16* __restrict__ vtb,
             int M, int N, int K) {
  __shared__ u16 smem[6][4096];           // A0 A1 A2 B0 B1 B2, 8 KB each (48 KB)
  const int nbm = M >> 7, nbn = N >> 7;
  const int nwg = nbm * nbn;
  const int bid = blockIdx.x;
  const int chunk = nwg >> 3;
  const int swz = (bid & 7) * chunk + (bid >> 3);
  const int gsz = GROUP_M * nbn;
  const int grp = swz / gsz, rem = swz % gsz;
  const int by = grp * GROUP_M + (rem % GROUP_M);
  const int bx = rem / GROUP_M;
  const int m0 = by * 128, n0 = bx * 128;

  const int tid = threadIdx.x, lane = tid & 63, w = tid >> 6;
  const int wr = w >> 1, wc = w & 1;
  const int frow = lane & 15, fk = (lane >> 4) * 8;
  const int srow = lane >> 2, scol = (lane & 3) * 8;

  f32x4 acc[4][4];
  #pragma unroll
  for (int i = 0; i < 4; ++i)
    #pragma unroll
    for (int j = 0; j < 4; ++j) acc[i][j] = (f32x4)0.0f;

  auto stage = [&](int d, int k0) {
    gload16(&A [(size_t)(m0 + w * 32 +      srow) * K + k0 + scol], smem[d] + w * 1024);
    gload16(&A [(size_t)(m0 + w * 32 + 16 + srow) * K + k0 + scol], smem[d] + w * 1024 + 512);
    gload16(&Bt[(size_t)(n0 + w * 32 +      srow) * K + k0 + scol], smem[3 + d] + w * 1024);
    gload16(&Bt[(size_t)(n0 + w * 32 + 16 + srow) * K + k0 + scol], smem[3 + d] + w * 1024 + 512);
  };

  const int NT = K >> 5;
  stage(0, 0); stage(1, 32); stage(2, 64);

  int cur = 0;
  for (int kt = 0; kt < NT; ++kt) {
    if (kt + 3 <= NT)      { VMW(8); }
    else if (kt + 2 == NT) { VMW(4); }
    else                   { VMW(0); }
    BAR();

    bf16x8 af[4], bfr[4];
    #pragma unroll
    for (int mi = 0; mi < 4; ++mi)
      af[mi] = *reinterpret_cast<const bf16x8*>(&smem[cur][(wr * 64 + mi * 16 + frow) * 32 + fk]);
    #pragma unroll
    for (int ni = 0; ni < 4; ++ni)
      bfr[ni] = *reinterpret_cast<const bf16x8*>(&smem[3 + cur][(wc * 64 + ni * 16 + frow) * 32 + fk]);
    #pragma unroll
    for (int mi = 0; mi < 4; ++mi)
      #pragma unroll
      for (int ni = 0; ni < 4; ++ni)
        acc[mi][ni] = __builtin_amdgcn_mfma_f32_16x16x32_bf16(af[mi], bfr[ni], acc[mi][ni], 0, 0, 0);

    BAR();
    if (kt + 3 < NT) stage(cur, (kt + 3) << 5);
    cur = (cur == 2) ? 0 : cur + 1;
  }

  u16* outb = (u16*)Cout;
  float* outf = (float*)Cout;

  if constexpr (MODE == 1) {
    // LDS-transpose epilogue: stage raw fp32 acc in 64-row halves (32 KB),
    // read back coalesced; bias+residual applied in read phase.
    char* ef = (char*)smem;
    #pragma unroll
    for (int h = 0; h < 2; ++h) {
      if (wr == h) {
        #pragma unroll
        for (int mi = 0; mi < 4; ++mi)
          #pragma unroll
          for (int ni = 0; ni < 4; ++ni) {
            int rl0 = mi * 16 + ((lane >> 4) << 2);
            int cl = wc * 64 + ni * 16 + (lane & 15);
            #pragma unroll
            for (int r = 0; r < 4; ++r) {
              int rl = rl0 + r;
              *(float*)(ef + rl * 512 + ((cl * 4) ^ ((rl & 7) << 4))) = acc[mi][ni][r];
            }
          }
      }
      BAR();
      {
        int row = tid >> 2;
        int s = (row & 7) << 4;
        #pragma unroll
        for (int j = 0; j < 8; ++j) {
          int g = (tid & 3) + 4 * j;
          float4 v = *reinterpret_cast<float4*>(ef + row * 512 + ((g * 16) ^ s));
          int ocol = n0 + g * 4;
          float4 bv4 = *reinterpret_cast<const float4*>(&bias[ocol]);
          size_t off = (size_t)(m0 + h * 64 + row) * N + ocol;
          float4 rv = *reinterpret_cast<const float4*>(&resid[off]);
          float4 o;
          o.x = v.x + bv4.x + rv.x; o.y = v.y + bv4.y + rv.y;
          o.z = v.z + bv4.z + rv.z; o.w = v.w + bv4.w + rv.w;
          *reinterpret_cast<float4*>(&outf[off]) = o;
        }
      }
      BAR();
    }
    return;
  }

  if constexpr (MODE == 2) {
    // gelu(acc+bias) -> bf16, LDS-staged (32 KB) then 256B-run uint4 stores
    char* ef = (char*)smem;
    #pragma unroll
    for (int mi = 0; mi < 4; ++mi)
      #pragma unroll
      for (int ni = 0; ni < 4; ++ni) {
        int rl0 = wr * 64 + mi * 16 + ((lane >> 4) << 2);
        int cl = wc * 64 + ni * 16 + (lane & 15);
        float bv = bias[n0 + cl];
        #pragma unroll
        for (int r = 0; r < 4; ++r) {
          int rl = rl0 + r;
          *(u16*)(ef + rl * 256 + ((cl * 2) ^ ((rl & 7) << 4))) = f2bf(gelu_f(acc[mi][ni][r] + bv));
        }
      }
    BAR();
    int cc = tid & 15;
    #pragma unroll
    for (int j = 0; j < 8; ++j) {
      int rr = (tid >> 4) + 16 * j;
      uint4 v = *reinterpret_cast<uint4*>(ef + rr * 256 + ((cc * 16) ^ ((rr & 7) << 4)));
      *reinterpret_cast<uint4*>(&outb[(size_t)(m0 + rr) * N + n0 + cc * 8]) = v;
    }
    return;
  }

  if constexpr (MODE == 4) {
    const bool vblk = (n0 >= 2 * C_);
    if (!vblk) {
      char* ef = (char*)smem;
      #pragma unroll
      for (int mi = 0; mi < 4; ++mi)
        #pragma unroll
        for (int ni = 0; ni < 4; ++ni) {
          int rl0 = wr * 64 + mi * 16 + ((lane >> 4) << 2);
          int cl = wc * 64 + ni * 16 + (lane & 15);
          #pragma unroll
          for (int r = 0; r < 4; ++r) {
            int rl = rl0 + r;
            *(u16*)(ef + rl * 256 + ((cl * 2) ^ ((rl & 7) << 4))) = f2bf(acc[mi][ni][r]);
          }
        }
      BAR();
      int cc = tid & 15;
      #pragma unroll
      for (int j = 0; j < 8; ++j) {
        int rr = (tid >> 4) + 16 * j;
        uint4 v = *reinterpret_cast<uint4*>(ef + rr * 256 + ((cc * 16) ^ ((rr & 7) << 4)));
        *reinterpret_cast<uint4*>(&outb[(size_t)(m0 + rr) * (2 * C_) + n0 + cc * 8]) = v;
      }
    } else {
      #pragma unroll
      for (int mi = 0; mi < 4; ++mi)
        #pragma unroll
        for (int ni = 0; ni < 4; ++ni) {
          int orow = m0 + wr * 64 + mi * 16 + ((lane >> 4) << 2);
          int ocol = n0 + wc * 64 + ni * 16 + (lane & 15);
          int vcol = ocol - 2 * C_;
          int hh = vcol >> 6, d = vcol & 63;
          int bb = orow >> 10, t0 = orow & (T_ - 1);
          union { u16 u[4]; uint2 v2; } pk;
          #pragma unroll
          for (int r = 0; r < 4; ++r) pk.u[r] = f2bf(acc[mi][ni][r]);
          *reinterpret_cast<uint2*>(
              &vtb[(((size_t)bb * H_ + hh) * HD_ + d) * T_ + t0]) = pk.v2;
        }
    }
    return;
  }

  // MODE 0 / MODE 3: direct stores
  #pragma unroll
  for (int mi = 0; mi < 4; ++mi) {
    #pragma unroll
    for (int ni = 0; ni < 4; ++ni) {
      int orow = m0 + wr * 64 + mi * 16 + ((lane >> 4) << 2);
      int ocol = n0 + wc * 64 + ni * 16 + (lane & 15);
      float bv = 0.0f;
      if constexpr (MODE == 3) bv = bias[ocol];
      #pragma unroll
      for (int r = 0; r < 4; ++r) {
        size_t off = (size_t)(orow + r) * N + ocol;
        float val = acc[mi][ni][r] + bv;
        if constexpr (MODE == 0) {
          outb[off] = f2bf(val);
        } else {
          outf[off] = val;
        }
      }
    }
  }
}

// ---------------------------------------------------------------- legacy GEMM (fallback)
template <int MODE>
__global__ __launch_bounds__(256)
void gemm_legacy(const u16* __restrict__ A, const float* __restrict__ Bw,
                 const float* __restrict__ bias, const float* __restrict__ resid,
                 void* __restrict__ Cout, int M, int N, int K) {
  __shared__ u16 As[128][40];
  __shared__ u16 Bs[128][40];
  const int m0 = blockIdx.y * 128, n0 = blockIdx.x * 128;
  const int tid = threadIdx.x, lane = tid & 63, w = tid >> 6;
  const int wr = w >> 1, wc = w & 1;
  const int row = lane & 15, kk8 = (lane >> 4) * 8;
  f32x4 acc[4][4];
  #pragma unroll
  for (int i = 0; i < 4; ++i)
    #pragma unroll
    for (int j = 0; j < 4; ++j) acc[i][j] = (f32x4)0.0f;
  for (int k0 = 0; k0 < K; k0 += 32) {
    #pragma unroll
    for (int i = 0; i < 2; ++i) {
      int e = (tid + i * 256) * 8;
      int r = e >> 5, c = e & 31;
      *reinterpret_cast<uint4*>(&As[r][c]) =
        *reinterpret_cast<const uint4*>(&A[(size_t)(m0 + r) * K + k0 + c]);
    }
    #pragma unroll
    for (int i = 0; i < 4; ++i) {
      int e = (tid + i * 256) * 4;
      int kr = e >> 7, c = e & 127;
      float4 bv = *reinterpret_cast<const float4*>(&Bw[(size_t)(k0 + kr) * N + n0 + c]);
      Bs[c + 0][kr] = f2bf(bv.x);
      Bs[c + 1][kr] = f2bf(bv.y);
      Bs[c + 2][kr] = f2bf(bv.z);
      Bs[c + 3][kr] = f2bf(bv.w);
    }
    __syncthreads();
    bf16x8 af[4], bfr[4];
    #pragma unroll
    for (int mi = 0; mi < 4; ++mi)
      af[mi] = *reinterpret_cast<const bf16x8*>(&As[wr * 64 + mi * 16 + row][kk8]);
    #pragma unroll
    for (int ni = 0; ni < 4; ++ni)
      bfr[ni] = *reinterpret_cast<const bf16x8*>(&Bs[wc * 64 + ni * 16 + row][kk8]);
    #pragma unroll
    for (int mi = 0; mi < 4; ++mi)
      #pragma unroll
      for (int ni = 0; ni < 4; ++ni)
        acc[mi][ni] = __builtin_amdgcn_mfma_f32_16x16x32_bf16(af[mi], bfr[ni], acc[mi][ni], 0, 0, 0);
    __syncthreads();
  }
  u16* outb = (u16*)Cout;
  float* outf = (float*)Cout;
  #pragma unroll
  for (int mi = 0; mi < 4; ++mi) {
    #pragma unroll
    for (int ni = 0; ni < 4; ++ni) {
      int orow = m0 + wr * 64 + mi * 16 + ((lane >> 4) << 2);
      int ocol = n0 + wc * 64 + ni * 16 + (lane & 15);
      float bv = 0.0f;
      if constexpr (MODE != 0) bv = bias[ocol];
      #pragma unroll
      for (int r = 0; r < 4; ++r) {
        size_t off = (size_t)(orow + r) * N + ocol;
        float val = acc[mi][ni][r] + bv;
        if constexpr (MODE == 0) outb[off] = f2bf(val);
        else if constexpr (MODE == 1) outf[off] = val + resid[off];
        else if constexpr (MODE == 2) {
          outb[off] = f2bf(gelu_f(val));
        } else outf[off] = val;
      }
    }
  }
}

// ---------------------------------------------------------------- attention v3 (unchanged)
__global__ __launch_bounds__(512)
void attn_kernel(const u16* __restrict__ qg, const u16* __restrict__ kg,
                 const u16* __restrict__ vt, u16* __restrict__ og) {
  const int bh = blockIdx.y;
  const int q0 = blockIdx.x * 128;
  const int b = bh >> 4;
  const int tid = threadIdx.x, lane = tid & 63, w = tid >> 6;
  const int fr = lane & 15, kk8 = (lane >> 4) * 8;
  __shared__ u16 KS[2][4096];
  __shared__ u16 VS[2][4096];
  __shared__ u16 Ps[8][16][72];

  const int ldq = 2 * C_;
  const size_t baseq = ((size_t)b * T_) * ldq + (bh & 15) * HD_;
  const u16* qbase = qg + baseq;
  const u16* kbase = kg + baseq;
  const u16* vbase = vt + ((size_t)bh * HD_) * T_;
  const size_t baseo = ((size_t)b * T_) * C_ + (bh & 15) * HD_;
  const int qw = q0 + w * 16;

  bf16x8 qf[2];
  #pragma unroll
  for (int s = 0; s < 2; ++s)
    qf[s] = *reinterpret_cast<const bf16x8*>(&qbase[(size_t)(qw + fr) * ldq + s * 32 + kk8]);

  const int srow8 = lane >> 3;
  const int scol = 8 * ((lane & 7) ^ srow8);
  auto stageKV = [&](int d, int kv0) {
    int rr = w * 8 + srow8;
    gload16(kbase + (size_t)(kv0 + rr) * ldq + scol, &KS[d][w * 512]);
    gload16(vbase + (size_t)rr * T_ + kv0 + scol,    &VS[d][w * 512]);
  };
  auto ldS = [&](const u16* base, int row, int cu) -> bf16x8 {
    return *reinterpret_cast<const bf16x8*>(&base[row * 64 + (cu ^ ((row & 7) << 3))]);
  };

  f32x4 acc_o[4];
  #pragma unroll
  for (int dt = 0; dt < 4; ++dt) acc_o[dt] = (f32x4)0.0f;
  float m_run[4] = {-1e30f, -1e30f, -1e30f, -1e30f};
  float l_run[4] = {0.f, 0.f, 0.f, 0.f};
  const float scale = 0.125f;

  const int kv_end = q0 + 128;
  stageKV(0, 0);
  VMW(0); BAR();

  int cur = 0;
  for (int kv0 = 0; kv0 < kv_end; kv0 += 64, cur ^= 1) {
    if (kv0 + 64 < kv_end) stageKV(cur ^ 1, kv0 + 64);

    f32x4 sacc[4];
    #pragma unroll
    for (int nt = 0; nt < 4; ++nt) sacc[nt] = (f32x4)0.0f;
    #pragma unroll
    for (int nt = 0; nt < 4; ++nt)
      #pragma unroll
      for (int s = 0; s < 2; ++s) {
        bf16x8 kf = ldS(KS[cur], nt * 16 + fr, s * 32 + kk8);
        sacc[nt] = __builtin_amdgcn_mfma_f32_16x16x32_bf16(qf[s], kf, sacc[nt], 0, 0, 0);
      }

    #pragma unroll
    for (int i = 0; i < 4; ++i) {
      int qrow = qw + ((lane >> 4) << 2) + i;
      float sv[4], pv[4];
      #pragma unroll
      for (int nt = 0; nt < 4; ++nt) {
        sv[nt] = sacc[nt][i] * scale;
        if (kv0 + nt * 16 + (lane & 15) > qrow) sv[nt] = -1e30f;
      }
      float mx = fmaxf(fmaxf(sv[0], sv[1]), fmaxf(sv[2], sv[3]));
      #pragma unroll
      for (int d = 1; d < 16; d <<= 1) mx = fmaxf(mx, __shfl_xor(mx, d, 64));
      float mnew = fmaxf(m_run[i], mx);
      float rsum = 0.0f;
      #pragma unroll
      for (int nt = 0; nt < 4; ++nt) { pv[nt] = __expf(sv[nt] - mnew); rsum += pv[nt]; }
      float alpha = __expf(m_run[i] - mnew);
      #pragma unroll
      for (int d = 1; d < 16; d <<= 1) rsum += __shfl_xor(rsum, d, 64);
      l_run[i] = l_run[i] * alpha + rsum;
      m_run[i] = mnew;
      #pragma unroll
      for (int dt = 0; dt < 4; ++dt) acc_o[dt][i] *= alpha;
      #pragma unroll
      for (int nt = 0; nt < 4; ++nt)
        Ps[w][((lane >> 4) << 2) + i][(lane & 15) + nt * 16] = f2bf(pv[nt]);
    }

    #pragma unroll
    for (int dt = 0; dt < 4; ++dt)
      #pragma unroll
      for (int s = 0; s < 2; ++s) {
        bf16x8 pf = *reinterpret_cast<const bf16x8*>(&Ps[w][fr][s * 32 + kk8]);
        bf16x8 vf = ldS(VS[cur], dt * 16 + fr, s * 32 + kk8);
        acc_o[dt] = __builtin_amdgcn_mfma_f32_16x16x32_bf16(pf, vf, acc_o[dt], 0, 0, 0);
      }
    VMW(0); BAR();
  }

  #pragma unroll
  for (int dt = 0; dt < 4; ++dt)
    #pragma unroll
    for (int i = 0; i < 4; ++i) {
      int r = qw + ((lane >> 4) << 2) + i;
      float val = acc_o[dt][i] / l_run[i];
      og[baseo + (size_t)r * C_ + dt * 16 + (lane & 15)] = f2bf(val);
    }
}

// ---------------------------------------------------------------- attention legacy (fallback path)
__global__ __launch_bounds__(256)
void attn_legacy(const u16* __restrict__ qg, const u16* __restrict__ kg,
                 const u16* __restrict__ vg, u16* __restrict__ og, int ldq) {
  const int bh = blockIdx.y;
  const int b = bh >> 4, hh = bh & 15;
  const int q0 = blockIdx.x * 64;
  const int tid = threadIdx.x, lane = tid & 63, w = tid >> 6;
  const int row = lane & 15, kk8 = (lane >> 4) * 8;
  __shared__ u16 Ks[64][72];
  __shared__ u16 Vt[64][72];
  __shared__ u16 Ps[4][16][72];

  const size_t basei = ((size_t)b * T_) * ldq + hh * HD_;
  const size_t baseo = ((size_t)b * T_) * C_ + hh * HD_;
  const int qw = q0 + w * 16;

  bf16x8 qf[2];
  #pragma unroll
  for (int s = 0; s < 2; ++s)
    qf[s] = *reinterpret_cast<const bf16x8*>(&qg[basei + (size_t)(qw + row) * ldq + s * 32 + kk8]);

  f32x4 acc_o[4];
  #pragma unroll
  for (int dt = 0; dt < 4; ++dt) acc_o[dt] = (f32x4)0.0f;
  float m_run[4] = {-1e30f, -1e30f, -1e30f, -1e30f};
  float l_run[4] = {0.f, 0.f, 0.f, 0.f};
  const float scale = 0.125f;

  const int sc = (tid & 7) * 8;
  const int kv_end = q0 + 64;
  for (int kv0 = 0; kv0 < kv_end; kv0 += 64) {
    #pragma unroll
    for (int p = 0; p < 2; ++p) {
      int sr = p * 32 + (tid >> 3);
      *reinterpret_cast<uint4*>(&Ks[sr][sc]) =
        *reinterpret_cast<const uint4*>(&kg[basei + (size_t)(kv0 + sr) * ldq + sc]);
      union { uint4 u4; u16 us[8]; } vv;
      vv.u4 = *reinterpret_cast<const uint4*>(&vg[basei + (size_t)(kv0 + sr) * ldq + sc]);
      #pragma unroll
      for (int j = 0; j < 8; ++j) Vt[sc + j][sr] = vv.us[j];
    }
    __syncthreads();

    f32x4 sacc[4];
    #pragma unroll
    for (int nt = 0; nt < 4; ++nt) sacc[nt] = (f32x4)0.0f;
    #pragma unroll
    for (int nt = 0; nt < 4; ++nt)
      #pragma unroll
      for (int s = 0; s < 2; ++s) {
        bf16x8 kf = *reinterpret_cast<const bf16x8*>(&Ks[nt * 16 + row][s * 32 + kk8]);
        sacc[nt] = __builtin_amdgcn_mfma_f32_16x16x32_bf16(qf[s], kf, sacc[nt], 0, 0, 0);
      }

    #pragma unroll
    for (int i = 0; i < 4; ++i) {
      int qrow = qw + ((lane >> 4) << 2) + i;
      float sv[4], pv[4];
      #pragma unroll
      for (int nt = 0; nt < 4; ++nt) {
        sv[nt] = sacc[nt][i] * scale;
        if (kv0 + nt * 16 + (lane & 15) > qrow) sv[nt] = -1e30f;
      }
      float mx = fmaxf(fmaxf(sv[0], sv[1]), fmaxf(sv[2], sv[3]));
      #pragma unroll
      for (int d = 1; d < 16; d <<= 1) mx = fmaxf(mx, __shfl_xor(mx, d, 64));
      float mnew = fmaxf(m_run[i], mx);
      float rsum = 0.0f;
      #pragma unroll
      for (int nt = 0; nt < 4; ++nt) { pv[nt] = __expf(sv[nt] - mnew); rsum += pv[nt]; }
      float alpha = __expf(m_run[i] - mnew);
      #pragma unroll
      for (int d = 1; d < 16; d <<= 1) rsum += __shfl_xor(rsum, d, 64);
      l_run[i] = l_run[i] * alpha + rsum;
      m_run[i] = mnew;
      #pragma unroll
      for (int nt = 0; nt < 4; ++nt)
        Ps[w][((lane >> 4) << 2) + i][(lane & 15) + nt * 16] = f2bf(pv[nt]);
      #pragma unroll
      for (int dt = 0; dt < 4; ++dt) acc_o[dt][i] *= alpha;
    }

    #pragma unroll
    for (int dt = 0; dt < 4; ++dt)
      #pragma unroll
      for (int s = 0; s < 2; ++s) {
        bf16x8 pf = *reinterpret_cast<const bf16x8*>(&Ps[w][row][s * 32 + kk8]);
        bf16x8 vf = *reinterpret_cast<const bf16x8*>(&Vt[dt * 16 + row][s * 32 + kk8]);
        acc_o[dt] = __builtin_amdgcn_mfma_f32_16x16x32_bf16(pf, vf, acc_o[dt], 0, 0, 0);
      }
    __syncthreads();
  }

  #pragma unroll
  for (int dt = 0; dt < 4; ++dt)
    #pragma unroll
    for (int i = 0; i < 4; ++i) {
      int r = qw + ((lane >> 4) << 2) + i;
      float val = acc_o[dt][i] / l_run[i];
      og[baseo + (size_t)r * C_ + dt * 16 + (lane & 15)] = f2bf(val);
    }
}

// ---------------------------------------------------------------- launch
extern "C" void kernel_launch(void* const* d_in, const int* in_sizes, int n_in,
                              void* d_out, int out_size, void* d_ws, size_t ws_size,
                              hipStream_t stream) {
  const int*   idx  = (const int*)d_in[0];
  const float* emb  = (const float*)d_in[1];
  const float* pos  = (const float*)d_in[2];
  const float* Wq   = (const float*)d_in[3];
  const float* Wk   = (const float*)d_in[4];
  const float* Wv   = (const float*)d_in[5];
  const float* Wo   = (const float*)d_in[6];
  const float* bo   = (const float*)d_in[7];
  const float* W1   = (const float*)d_in[8];
  const float* b1   = (const float*)d_in[9];
  const float* W2   = (const float*)d_in[10];
  const float* b2   = (const float*)d_in[11];
  const float* ln1g = (const float*)d_in[12];
  const float* ln1b = (const float*)d_in[13];
  const float* ln2g = (const float*)d_in[14];
  const float* ln2b = (const float*)d_in[15];
  const float* lnfg = (const float*)d_in[16];
  const float* lnfb = (const float*)d_in[17];
  const float* Wlm  = (const float*)d_in[18];
  const float* blm  = (const float*)d_in[19];

  char* ws = (char*)d_ws;
  float* x    = (float*)ws;                             // 16 MiB
  u16*   h    = (u16*)(ws + (16u << 20));               //  8 MiB
  u16*   qkv  = (u16*)(ws + (24u << 20));               // 16 MiB [M][2C] (Q,K)
  u16*   vtb  = (u16*)(ws + (40u << 20));               //  8 MiB [B][H][64][T]
  u16*   ob   = (u16*)(ws + (48u << 20));               //  8 MiB
  u16*   ffb  = (u16*)(ws + (24u << 20));               // 32 MiB alias qkv+vtb+ob (dead)

  u16* WqkvT = (u16*)(ws + (56u  << 20));               // 24 MiB (L*3C*C)
  u16* WoT   = (u16*)(ws + (80u  << 20));               //  8 MiB
  u16* W1T   = (u16*)(ws + (88u  << 20));               // 32 MiB (L*FF*C)
  u16* W2T   = (u16*)(ws + (120u << 20));               // 32 MiB (L*C*FF)
  u16* WlmT  = (u16*)(ws + (152u << 20));               // 62.5 MiB (V*C)
  const size_t WS_NEED = (152ull << 20) + 2ull * C_ * V_;

  dim3 blk(256), blkA(512);
  const int nQKV  = (M_ / 128) * (3 * C_ / 128);  // 768
  const int nCC   = (M_ / 128) * (C_ / 128);      // 256
  const int nF1   = (M_ / 128) * (FF_ / 128);     // 1024
  const int nLM   = (M_ / 128) * (V_ / 128);      // 8000
  dim3 gA(T_ / 128, B_ * H_);                     // 8 x 64

  if (ws_size >= WS_NEED) {
    const size_t s3 = (size_t)3 * C_ * C_;
    embed_kernel<1><<<M_, blk, 0, stream>>>(idx, emb, pos, x, ln1g, ln1b, h);
    wtrans4_kernel<<<dim3(C_ / 32, C_ / 32, 16), blk, 0, stream>>>(Wq, Wk, Wv, Wo, WqkvT, WoT);
    wtrans_kernel<<<dim3(FF_ / 32, C_ / 32, L_), blk, 0, stream>>>(W1, W1T, C_, FF_, (size_t)C_ * FF_);
    wtrans_kernel<<<dim3(C_ / 32, FF_ / 32, L_), blk, 0, stream>>>(W2, W2T, FF_, C_, (size_t)C_ * FF_);
    wtrans_kernel<<<dim3(V_ / 32,  C_ / 32, 1),  blk, 0, stream>>>(Wlm, WlmT, C_, V_, (size_t)C_ * V_);

    for (int l = 0; l < L_; ++l) {
      if (l > 0)
        ln_kernel<<<M_ / 4, blk, 0, stream>>>(x, ln1g + l * C_, ln1b + l * C_, h);
      gemm_bt<4, 8><<<nQKV, blk, 0, stream>>>(h, WqkvT + (size_t)l * s3, nullptr, nullptr, qkv, vtb, M_, 3 * C_, C_);
      attn_kernel<<<gA, blkA, 0, stream>>>(qkv, qkv + C_, vtb, ob);
      gemm_bt<1, 8><<<nCC, blk, 0, stream>>>(ob, WoT + (size_t)l * C_ * C_, bo + l * C_, x, x, nullptr, M_, C_, C_);
      ln_kernel<<<M_ / 4, blk, 0, stream>>>(x, ln2g + l * C_, ln2b + l * C_, h);
      gemm_bt<2, 8><<<nF1, blk, 0, stream>>>(h, W1T + (size_t)l * C_ * FF_, b1 + l * FF_, nullptr, ffb, nullptr, M_, FF_, C_);
      gemm_bt<1, 8><<<nCC, blk, 0, stream>>>(ffb, W2T + (size_t)l * C_ * FF_, b2 + l * C_, x, x, nullptr, M_, C_, FF_);
    }
    ln_kernel<<<M_ / 4, blk, 0, stream>>>(x, lnfg, lnfb, h);
    gemm_bt<3, 8><<<nLM, blk, 0, stream>>>(h, WlmT, blm, nullptr, (float*)d_out, nullptr, M_, V_, C_);
  } else {
    embed_kernel<0><<<M_, blk, 0, stream>>>(idx, emb, pos, x, nullptr, nullptr, nullptr);
    float* xr = x;
    u16* qb = qkv;
    u16* kb = qkv + (size_t)M_ * C_;
    u16* vb = (u16*)(ws + (40u << 20));
    dim3 gC(C_ / 128, M_ / 128);
    dim3 gF(FF_ / 128, M_ / 128);
    dim3 gV(V_ / 128, M_ / 128);
    dim3 gAl(T_ / 64, B_ * H_);
    for (int l = 0; l < L_; ++l) {
      ln_kernel<<<M_ / 4, blk, 0, stream>>>(xr, ln1g + l * C_, ln1b + l * C_, h);
      gemm_legacy<0><<<gC, blk, 0, stream>>>(h, Wq + (size_t)l * C_ * C_, nullptr, nullptr, qb, M_, C_, C_);
      gemm_legacy<0><<<gC, blk, 0, stream>>>(h, Wk + (size_t)l * C_ * C_, nullptr, nullptr, kb, M_, C_, C_);
      gemm_legacy<0><<<gC, blk, 0, stream>>>(h, Wv + (size_t)l * C_ * C_, nullptr, nullptr, vb, M_, C_, C_);
      attn_legacy<<<gAl, blk, 0, stream>>>(qb, kb, vb, ob, C_);
      gemm_legacy<1><<<gC, blk, 0, stream>>>(ob, Wo + (size_t)l * C_ * C_, bo + l * C_, xr, xr, M_, C_, C_);
      ln_kernel<<<M_ / 4, blk, 0, stream>>>(xr, ln2g + l * C_, ln2b + l * C_, h);
      gemm_legacy<2><<<gF, blk, 0, stream>>>(h, W1 + (size_t)l * C_ * FF_, b1 + l * FF_, nullptr, ffb, M_, FF_, C_);
      gemm_legacy<1><<<gC, blk, 0, stream>>>(ffb, W2 + (size_t)l * FF_ * C_, b2 + l * C_, xr, xr, M_, C_, FF_);
    }
    ln_kernel<<<M_ / 4, blk, 0, stream>>>(xr, lnfg, lnfb, h);
    gemm_legacy<3><<<gV, blk, 0, stream>>>(h, Wlm, blm, nullptr, (float*)d_out, M_, V_, C_);
  }
}

// Round 13
// 1347.432 us; speedup vs baseline: 1.0641x; 1.0641x over previous
//
#include <hip/hip_runtime.h>

#define V_  32000
#define C_  1024
#define T_  1024
#define H_  16
#define L_  4
#define B_  4
#define HD_ 64
#define FF_ 4096
#define M_  (B_ * T_)   // 4096 token rows

typedef __attribute__((ext_vector_type(8))) short bf16x8;
typedef __attribute__((ext_vector_type(4))) float f32x4;
typedef unsigned short u16;

#define FENCE() asm volatile("" ::: "memory")
#define BAR()  do { FENCE(); __builtin_amdgcn_s_barrier(); FENCE(); } while (0)
#define VMW(n) asm volatile("s_waitcnt vmcnt(" #n ")" ::: "memory")

__device__ __forceinline__ u16 f2bf(float f) {
  unsigned u = __builtin_bit_cast(unsigned, f);
  u += 0x7fffu + ((u >> 16) & 1u);        // round-to-nearest-even
  return (u16)(u >> 16);
}

__device__ __forceinline__ float gelu_f(float v) {
  return 0.5f * v * (1.0f + erff(v * 0.70710678118654752f));
}

__device__ __forceinline__ void gload16(const u16* g, u16* l) {
  __builtin_amdgcn_global_load_lds(
      (const __attribute__((address_space(1))) void*)g,
      (__attribute__((address_space(3))) void*)l, 16, 0, 0);
}

// ---------------------------------------------------------------- embedding (+ optional fused LN)
template <int FUSE_LN>
__global__ __launch_bounds__(256)
void embed_kernel(const int* __restrict__ idx, const float* __restrict__ emb,
                  const float* __restrict__ pos, float* __restrict__ x,
                  const float* __restrict__ g, const float* __restrict__ bta,
                  u16* __restrict__ hout) {
  int row = blockIdx.x;
  int t = row & (T_ - 1);
  int tok = idx[row];
  float4 e = reinterpret_cast<const float4*>(emb + (size_t)tok * C_)[threadIdx.x];
  float4 p = reinterpret_cast<const float4*>(pos + (size_t)t * C_)[threadIdx.x];
  float4 r;
  r.x = e.x + p.x; r.y = e.y + p.y; r.z = e.z + p.z; r.w = e.w + p.w;
  reinterpret_cast<float4*>(x + (size_t)row * C_)[threadIdx.x] = r;
  if constexpr (FUSE_LN) {
    int tid = threadIdx.x;
    float s  = r.x + r.y + r.z + r.w;
    float ss = r.x * r.x + r.y * r.y + r.z * r.z + r.w * r.w;
    #pragma unroll
    for (int d = 1; d < 64; d <<= 1) {
      s  += __shfl_xor(s, d, 64);
      ss += __shfl_xor(ss, d, 64);
    }
    __shared__ float rs[4], rss[4];
    int w = tid >> 6, lane = tid & 63;
    if (lane == 0) { rs[w] = s; rss[w] = ss; }
    __syncthreads();
    s  = rs[0] + rs[1] + rs[2] + rs[3];
    ss = rss[0] + rss[1] + rss[2] + rss[3];
    float mean = s * (1.0f / C_);
    float var  = ss * (1.0f / C_) - mean * mean;
    float rstd = rsqrtf(var + 1e-5f);
    float4 gv = reinterpret_cast<const float4*>(g)[tid];
    float4 bv = reinterpret_cast<const float4*>(bta)[tid];
    union { u16 u[4]; uint2 v; } pk;
    pk.u[0] = f2bf((r.x - mean) * rstd * gv.x + bv.x);
    pk.u[1] = f2bf((r.y - mean) * rstd * gv.y + bv.y);
    pk.u[2] = f2bf((r.z - mean) * rstd * gv.z + bv.z);
    pk.u[3] = f2bf((r.w - mean) * rstd * gv.w + bv.w);
    *reinterpret_cast<uint2*>(&hout[(size_t)row * C_ + tid * 4]) = pk.v;
  }
}

// ---------------------------------------------------------------- layernorm (1 wave / row)
__global__ __launch_bounds__(256)
void ln_kernel(const float* __restrict__ xin, const float* __restrict__ g,
               const float* __restrict__ bta, u16* __restrict__ out) {
  const int w = threadIdx.x >> 6, lane = threadIdx.x & 63;
  const int row = blockIdx.x * 4 + w;
  const float4* xr = reinterpret_cast<const float4*>(xin + (size_t)row * C_);
  float4 xv[4];
  float s = 0.f, ss = 0.f;
  #pragma unroll
  for (int j = 0; j < 4; ++j) {
    xv[j] = xr[lane + 64 * j];
    s  += xv[j].x + xv[j].y + xv[j].z + xv[j].w;
    ss += xv[j].x * xv[j].x + xv[j].y * xv[j].y + xv[j].z * xv[j].z + xv[j].w * xv[j].w;
  }
  #pragma unroll
  for (int d = 1; d < 64; d <<= 1) {
    s  += __shfl_xor(s, d, 64);
    ss += __shfl_xor(ss, d, 64);
  }
  float mean = s * (1.0f / C_);
  float var  = ss * (1.0f / C_) - mean * mean;
  float rstd = rsqrtf(var + 1e-5f);
  #pragma unroll
  for (int j = 0; j < 4; ++j) {
    float4 gv = reinterpret_cast<const float4*>(g)[lane + 64 * j];
    float4 bv = reinterpret_cast<const float4*>(bta)[lane + 64 * j];
    union { u16 u[4]; uint2 v; } pk;
    pk.u[0] = f2bf((xv[j].x - mean) * rstd * gv.x + bv.x);
    pk.u[1] = f2bf((xv[j].y - mean) * rstd * gv.y + bv.y);
    pk.u[2] = f2bf((xv[j].z - mean) * rstd * gv.z + bv.z);
    pk.u[3] = f2bf((xv[j].w - mean) * rstd * gv.w + bv.w);
    *reinterpret_cast<uint2*>(&out[(size_t)row * C_ + (lane + 64 * j) * 4]) = pk.v;
  }
}

// ---------------------------------------------------------------- weight transpose+convert (generic)
__global__ __launch_bounds__(256)
void wtrans_kernel(const float* __restrict__ W, u16* __restrict__ Wt, int K, int N,
                   size_t dstBS) {
  const float* src = W + (size_t)blockIdx.z * K * N;
  u16* dst = Wt + (size_t)blockIdx.z * dstBS;
  __shared__ float tile[32][33];
  int k0 = blockIdx.y * 32, n0 = blockIdx.x * 32;
  int tx = threadIdx.x & 31, ty = threadIdx.x >> 5;
  #pragma unroll
  for (int i = 0; i < 4; ++i)
    tile[ty * 4 + i][tx] = src[(size_t)(k0 + ty * 4 + i) * N + n0 + tx];
  __syncthreads();
  int n = threadIdx.x >> 3, q = threadIdx.x & 7;
  union { u16 u[4]; uint2 v; } pk;
  #pragma unroll
  for (int j = 0; j < 4; ++j) pk.u[j] = f2bf(tile[4 * q + j][n]);
  *reinterpret_cast<uint2*>(&dst[(size_t)(n0 + n) * K + k0 + 4 * q]) = pk.v;
}

// merged C_xC_ transpose: z = 16 slices (layer = z&3, which = z>>2: q,k,v,o)
__global__ __launch_bounds__(256)
void wtrans4_kernel(const float* __restrict__ Wq, const float* __restrict__ Wk,
                    const float* __restrict__ Wv, const float* __restrict__ Wo,
                    u16* __restrict__ WqkvT, u16* __restrict__ WoT) {
  int zz = blockIdx.z;
  int l = zz & 3, which = zz >> 2;
  const float* src = (which == 0 ? Wq : which == 1 ? Wk : which == 2 ? Wv : Wo)
                     + (size_t)l * C_ * C_;
  u16* dst = (which == 3)
      ? WoT + (size_t)l * C_ * C_
      : WqkvT + (size_t)l * 3 * C_ * C_ + (size_t)which * C_ * C_;
  __shared__ float tile[32][33];
  int k0 = blockIdx.y * 32, n0 = blockIdx.x * 32;
  int tx = threadIdx.x & 31, ty = threadIdx.x >> 5;
  #pragma unroll
  for (int i = 0; i < 4; ++i)
    tile[ty * 4 + i][tx] = src[(size_t)(k0 + ty * 4 + i) * C_ + n0 + tx];
  __syncthreads();
  int n = threadIdx.x >> 3, q = threadIdx.x & 7;
  union { u16 u[4]; uint2 v; } pk;
  #pragma unroll
  for (int j = 0; j < 4; ++j) pk.u[j] = f2bf(tile[4 * q + j][n]);
  *reinterpret_cast<uint2*>(&dst[(size_t)(n0 + n) * C_ + k0 + 4 * q]) = pk.v;
}

// ---------------------------------------------------------------- GEMM 128x128, 3-deep pipelined
// MODE 1: fp32 = acc + bias + residual (Wo, W2) -- LDS-transpose epilogue
// MODE 4: QKV fused: Q/K -> bf16 stride 2C (LDS-staged); V -> vtb[b][h][d][t]
//         (V also LDS-staged transposed -> coalesced 256B t-runs)
template <int MODE, int GROUP_M>
__global__ __launch_bounds__(256)
void gemm_bt(const u16* __restrict__ A, const u16* __restrict__ Bt,
             const float* __restrict__ bias, const float* __restrict__ resid,
             void* __restrict__ Cout, u16* __restrict__ vtb,
             int M, int N, int K) {
  __shared__ u16 smem[6][4096];           // A0 A1 A2 B0 B1 B2, 8 KB each (48 KB)
  const int nbm = M >> 7, nbn = N >> 7;
  const int nwg = nbm * nbn;
  const int bid = blockIdx.x;
  const int chunk = nwg >> 3;
  const int swz = (bid & 7) * chunk + (bid >> 3);
  const int gsz = GROUP_M * nbn;
  const int grp = swz / gsz, rem = swz % gsz;
  const int by = grp * GROUP_M + (rem % GROUP_M);
  const int bx = rem / GROUP_M;
  const int m0 = by * 128, n0 = bx * 128;

  const int tid = threadIdx.x, lane = tid & 63, w = tid >> 6;
  const int wr = w >> 1, wc = w & 1;
  const int frow = lane & 15, fk = (lane >> 4) * 8;
  const int srow = lane >> 2, scol = (lane & 3) * 8;

  f32x4 acc[4][4];
  #pragma unroll
  for (int i = 0; i < 4; ++i)
    #pragma unroll
    for (int j = 0; j < 4; ++j) acc[i][j] = (f32x4)0.0f;

  auto stage = [&](int d, int k0) {
    gload16(&A [(size_t)(m0 + w * 32 +      srow) * K + k0 + scol], smem[d] + w * 1024);
    gload16(&A [(size_t)(m0 + w * 32 + 16 + srow) * K + k0 + scol], smem[d] + w * 1024 + 512);
    gload16(&Bt[(size_t)(n0 + w * 32 +      srow) * K + k0 + scol], smem[3 + d] + w * 1024);
    gload16(&Bt[(size_t)(n0 + w * 32 + 16 + srow) * K + k0 + scol], smem[3 + d] + w * 1024 + 512);
  };

  const int NT = K >> 5;
  stage(0, 0); stage(1, 32); stage(2, 64);

  int cur = 0;
  for (int kt = 0; kt < NT; ++kt) {
    if (kt + 3 <= NT)      { VMW(8); }
    else if (kt + 2 == NT) { VMW(4); }
    else                   { VMW(0); }
    BAR();

    bf16x8 af[4], bfr[4];
    #pragma unroll
    for (int mi = 0; mi < 4; ++mi)
      af[mi] = *reinterpret_cast<const bf16x8*>(&smem[cur][(wr * 64 + mi * 16 + frow) * 32 + fk]);
    #pragma unroll
    for (int ni = 0; ni < 4; ++ni)
      bfr[ni] = *reinterpret_cast<const bf16x8*>(&smem[3 + cur][(wc * 64 + ni * 16 + frow) * 32 + fk]);
    #pragma unroll
    for (int mi = 0; mi < 4; ++mi)
      #pragma unroll
      for (int ni = 0; ni < 4; ++ni)
        acc[mi][ni] = __builtin_amdgcn_mfma_f32_16x16x32_bf16(af[mi], bfr[ni], acc[mi][ni], 0, 0, 0);

    BAR();
    if (kt + 3 < NT) stage(cur, (kt + 3) << 5);
    cur = (cur == 2) ? 0 : cur + 1;
  }

  u16* outb = (u16*)Cout;
  float* outf = (float*)Cout;

  if constexpr (MODE == 1) {
    // LDS-transpose epilogue: stage raw fp32 acc in 64-row halves (32 KB),
    // read back coalesced; bias+residual applied in read phase.
    char* ef = (char*)smem;
    #pragma unroll
    for (int h = 0; h < 2; ++h) {
      if (wr == h) {
        #pragma unroll
        for (int mi = 0; mi < 4; ++mi)
          #pragma unroll
          for (int ni = 0; ni < 4; ++ni) {
            int rl0 = mi * 16 + ((lane >> 4) << 2);
            int cl = wc * 64 + ni * 16 + (lane & 15);
            #pragma unroll
            for (int r = 0; r < 4; ++r) {
              int rl = rl0 + r;
              *(float*)(ef + rl * 512 + ((cl * 4) ^ ((rl & 7) << 4))) = acc[mi][ni][r];
            }
          }
      }
      BAR();
      {
        int row = tid >> 2;
        int s = (row & 7) << 4;
        #pragma unroll
        for (int j = 0; j < 8; ++j) {
          int g = (tid & 3) + 4 * j;
          float4 v = *reinterpret_cast<float4*>(ef + row * 512 + ((g * 16) ^ s));
          int ocol = n0 + g * 4;
          float4 bv4 = *reinterpret_cast<const float4*>(&bias[ocol]);
          size_t off = (size_t)(m0 + h * 64 + row) * N + ocol;
          float4 rv = *reinterpret_cast<const float4*>(&resid[off]);
          float4 o;
          o.x = v.x + bv4.x + rv.x; o.y = v.y + bv4.y + rv.y;
          o.z = v.z + bv4.z + rv.z; o.w = v.w + bv4.w + rv.w;
          *reinterpret_cast<float4*>(&outf[off]) = o;
        }
      }
      BAR();
    }
    return;
  }

  if constexpr (MODE == 4) {
    const bool vblk = (n0 >= 2 * C_);
    char* ef = (char*)smem;
    if (!vblk) {
      // Q/K: stage bf16 tile row-major, store coalesced uint4 in 256B row runs
      #pragma unroll
      for (int mi = 0; mi < 4; ++mi)
        #pragma unroll
        for (int ni = 0; ni < 4; ++ni) {
          int rl0 = wr * 64 + mi * 16 + ((lane >> 4) << 2);
          int cl = wc * 64 + ni * 16 + (lane & 15);
          #pragma unroll
          for (int r = 0; r < 4; ++r) {
            int rl = rl0 + r;
            *(u16*)(ef + rl * 256 + ((cl * 2) ^ ((rl & 7) << 4))) = f2bf(acc[mi][ni][r]);
          }
        }
      BAR();
      int cc = tid & 15;
      #pragma unroll
      for (int j = 0; j < 8; ++j) {
        int rr = (tid >> 4) + 16 * j;
        uint4 v = *reinterpret_cast<uint4*>(ef + rr * 256 + ((cc * 16) ^ ((rr & 7) << 4)));
        *reinterpret_cast<uint4*>(&outb[(size_t)(m0 + rr) * (2 * C_) + n0 + cc * 8]) = v;
      }
    } else {
      // V: stage bf16 tile TRANSPOSED (ef[cl][rl]), store coalesced uint4
      // along t (256B runs per (hh,d) output row)
      #pragma unroll
      for (int mi = 0; mi < 4; ++mi)
        #pragma unroll
        for (int ni = 0; ni < 4; ++ni) {
          int rl0 = wr * 64 + mi * 16 + ((lane >> 4) << 2);
          int cl = wc * 64 + ni * 16 + (lane & 15);
          #pragma unroll
          for (int r = 0; r < 4; ++r) {
            int rl = rl0 + r;
            *(u16*)(ef + cl * 256 + ((rl * 2) ^ ((cl & 7) << 4))) = f2bf(acc[mi][ni][r]);
          }
        }
      BAR();
      int cc = tid & 15;
      int bb = m0 >> 10, t0 = m0 & (T_ - 1);
      #pragma unroll
      for (int j = 0; j < 8; ++j) {
        int rr = (tid >> 4) + 16 * j;               // cl (head-dim col) 0..127
        uint4 v = *reinterpret_cast<uint4*>(ef + rr * 256 + ((cc * 16) ^ ((rr & 7) << 4)));
        int vcol = n0 - 2 * C_ + rr;
        int hh = vcol >> 6, d = vcol & 63;
        *reinterpret_cast<uint4*>(
            &vtb[(((size_t)bb * H_ + hh) * HD_ + d) * T_ + t0 + cc * 8]) = v;
      }
    }
    return;
  }

  // MODE 0 / MODE 3: direct stores
  #pragma unroll
  for (int mi = 0; mi < 4; ++mi) {
    #pragma unroll
    for (int ni = 0; ni < 4; ++ni) {
      int orow = m0 + wr * 64 + mi * 16 + ((lane >> 4) << 2);
      int ocol = n0 + wc * 64 + ni * 16 + (lane & 15);
      float bv = 0.0f;
      if constexpr (MODE == 3) bv = bias[ocol];
      #pragma unroll
      for (int r = 0; r < 4; ++r) {
        size_t off = (size_t)(orow + r) * N + ocol;
        float val = acc[mi][ni][r] + bv;
        if constexpr (MODE == 0) {
          outb[off] = f2bf(val);
        } else {
          outf[off] = val;
        }
      }
    }
  }
}

// ---------------------------------------------------------------- GEMM 256x256 8-phase (W1, LM)
// Direct-store epilogue (R8 form — proven best here).
template <int MODE>
__global__ __launch_bounds__(512, 2)
void gemm8(const u16* __restrict__ A, const u16* __restrict__ Bt,
           const float* __restrict__ bias, const float* __restrict__ resid,
           void* __restrict__ Cout, int M, int N, int K) {
  __shared__ u16 lds8[65536];
  const int nbm = M >> 8, nbn = N >> 8;
  const int nwg = nbm * nbn;
  const int chunk = nwg >> 3;
  const int bid = blockIdx.x;
  const int swz = (bid & 7) * chunk + (bid >> 3);
  const int gsz = 4 * nbn;
  const int grp = swz / gsz, rem = swz % gsz;
  const int by = grp * 4 + (rem & 3);
  const int bx = rem >> 2;
  const int m0 = by << 8, n0 = bx << 8;

  const int tid = threadIdx.x, lane = tid & 63, w = tid >> 6;
  const int wm = w >> 2, wn = w & 3;
  const int fr = lane & 15, kgb = (lane >> 4) * 16;
  const int scolz = 8 * ((lane & 7) ^ (lane >> 3));
  const int NT = K >> 6;
  const int NI = NT >> 1;

  f32x4 acc[8][4];
  #pragma unroll
  for (int i = 0; i < 8; ++i)
    #pragma unroll
    for (int j = 0; j < 4; ++j) acc[i][j] = (f32x4)0.0f;

  auto ldr = [&](int d, int isB, int row, int cb) -> bf16x8 {
    int bo = row * 128 + (cb ^ ((row & 7) << 4));
    const char* base = (const char*)lds8 + d * 65536 + isB * 32768 +
                       (isB ? (wn >> 1) : wm) * 16384;
    return *reinterpret_cast<const bf16x8*>(base + bo);
  };
  auto stage_half = [&](const u16* grow0, u16* ldst) {
    #pragma unroll
    for (int p = 0; p < 2; ++p) {
      int r = (p * 8 + w) * 8 + (lane >> 3);
      gload16(grow0 + (size_t)r * K + scolz, ldst + (p * 8 + w) * 512);
    }
  };
  auto stageA = [&](int d, int h, int t) {
    stage_half(&A[(size_t)(m0 + h * 128) * K + t * 64],
               lds8 + d * 32768 + h * 8192);
  };
  auto stageB = [&](int d, int h, int t) {
    stage_half(&Bt[(size_t)(n0 + h * 128) * K + t * 64],
               lds8 + d * 32768 + 16384 + h * 8192);
  };

  bf16x8 af[2][2], bfr[4][2];

#define LDA_Q(d, q) do {                                   \
    af[0][0] = ldr(d, 0, (q) * 32 + fr,      kgb);         \
    af[0][1] = ldr(d, 0, (q) * 32 + fr,      64 + kgb);    \
    af[1][0] = ldr(d, 0, (q) * 32 + 16 + fr, kgb);         \
    af[1][1] = ldr(d, 0, (q) * 32 + 16 + fr, 64 + kgb);    \
  } while (0)
#define LDB_ALL(d) do {                                    \
    _Pragma("unroll")                                      \
    for (int nj = 0; nj < 4; ++nj) {                       \
      bfr[nj][0] = ldr(d, 1, (wn & 1) * 64 + nj * 16 + fr, kgb);      \
      bfr[nj][1] = ldr(d, 1, (wn & 1) * 64 + nj * 16 + fr, 64 + kgb); \
    }                                                      \
  } while (0)
#define MFMA_Q(q) do {                                     \
    __builtin_amdgcn_s_setprio(1);                         \
    _Pragma("unroll")                                      \
    for (int lmi = 0; lmi < 2; ++lmi)                      \
      _Pragma("unroll")                                    \
      for (int nj = 0; nj < 4; ++nj)                       \
        _Pragma("unroll")                                  \
        for (int ks = 0; ks < 2; ++ks)                     \
          acc[2 * (q) + lmi][nj] = __builtin_amdgcn_mfma_f32_16x16x32_bf16( \
              af[lmi][ks], bfr[nj][ks], acc[2 * (q) + lmi][nj], 0, 0, 0);   \
    __builtin_amdgcn_s_setprio(0);                         \
  } while (0)

  stageB(0, 0, 0); stageB(0, 1, 0);
  stageA(0, 0, 0); stageA(0, 1, 0);
  stageB(1, 0, 1); stageB(1, 1, 1);
  VMW(4);
  BAR();

  for (int i = 0; i < NI; ++i) {
    const int a = 2 * i, b = 2 * i + 1;
    const bool pa = (a + 2 < NT), pb = (b + 2 < NT);
    LDB_ALL(0); LDA_Q(0, 0);
    stageA(1, 0, b);
    BAR(); MFMA_Q(0); BAR();
    LDA_Q(0, 1);
    stageA(1, 1, b);
    if (pa) stageB(0, 0, a + 2);
    BAR(); MFMA_Q(1); BAR();
    LDA_Q(0, 2);
    if (pa) stageB(0, 1, a + 2);
    BAR(); MFMA_Q(2); BAR();
    LDA_Q(0, 3);
    BAR(); MFMA_Q(3);
    if (pa) { VMW(4); } else { VMW(0); }
    BAR();
    LDB_ALL(1); LDA_Q(1, 0);
    if (pa) stageA(0, 0, a + 2);
    BAR(); MFMA_Q(0); BAR();
    LDA_Q(1, 1);
    if (pa) stageA(0, 1, a + 2);
    BAR(); MFMA_Q(1); BAR();
    LDA_Q(1, 2);
    if (pb) stageB(1, 0, b + 2);
    BAR(); MFMA_Q(2); BAR();
    LDA_Q(1, 3);
    if (pb) stageB(1, 1, b + 2);
    BAR(); MFMA_Q(3);
    if (pb) { VMW(4); } else { VMW(0); }
    BAR();
  }
#undef LDA_Q
#undef LDB_ALL
#undef MFMA_Q

  u16* outb = (u16*)Cout;
  float* outf = (float*)Cout;
  #pragma unroll
  for (int mi = 0; mi < 8; ++mi) {
    #pragma unroll
    for (int nj = 0; nj < 4; ++nj) {
      int orow = m0 + wm * 128 + mi * 16 + ((lane >> 4) << 2);
      int ocol = n0 + wn * 64 + nj * 16 + (lane & 15);
      float bv = 0.0f;
      if constexpr (MODE != 0) bv = bias[ocol];
      #pragma unroll
      for (int r = 0; r < 4; ++r) {
        size_t off = (size_t)(orow + r) * N + ocol;
        float val = acc[mi][nj][r] + bv;
        if constexpr (MODE == 0) {
          outb[off] = f2bf(val);
        } else if constexpr (MODE == 1) {
          outf[off] = val + resid[off];
        } else if constexpr (MODE == 2) {
          outb[off] = f2bf(gelu_f(val));
        } else {
          outf[off] = val;
        }
      }
    }
  }
}

// ---------------------------------------------------------------- legacy GEMM (fallback)
template <int MODE>
__global__ __launch_bounds__(256)
void gemm_legacy(const u16* __restrict__ A, const float* __restrict__ Bw,
                 const float* __restrict__ bias, const float* __restrict__ resid,
                 void* __restrict__ Cout, int M, int N, int K) {
  __shared__ u16 As[128][40];
  __shared__ u16 Bs[128][40];
  const int m0 = blockIdx.y * 128, n0 = blockIdx.x * 128;
  const int tid = threadIdx.x, lane = tid & 63, w = tid >> 6;
  const int wr = w >> 1, wc = w & 1;
  const int row = lane & 15, kk8 = (lane >> 4) * 8;
  f32x4 acc[4][4];
  #pragma unroll
  for (int i = 0; i < 4; ++i)
    #pragma unroll
    for (int j = 0; j < 4; ++j) acc[i][j] = (f32x4)0.0f;
  for (int k0 = 0; k0 < K; k0 += 32) {
    #pragma unroll
    for (int i = 0; i < 2; ++i) {
      int e = (tid + i * 256) * 8;
      int r = e >> 5, c = e & 31;
      *reinterpret_cast<uint4*>(&As[r][c]) =
        *reinterpret_cast<const uint4*>(&A[(size_t)(m0 + r) * K + k0 + c]);
    }
    #pragma unroll
    for (int i = 0; i < 4; ++i) {
      int e = (tid + i * 256) * 4;
      int kr = e >> 7, c = e & 127;
      float4 bv = *reinterpret_cast<const float4*>(&Bw[(size_t)(k0 + kr) * N + n0 + c]);
      Bs[c + 0][kr] = f2bf(bv.x);
      Bs[c + 1][kr] = f2bf(bv.y);
      Bs[c + 2][kr] = f2bf(bv.z);
      Bs[c + 3][kr] = f2bf(bv.w);
    }
    __syncthreads();
    bf16x8 af[4], bfr[4];
    #pragma unroll
    for (int mi = 0; mi < 4; ++mi)
      af[mi] = *reinterpret_cast<const bf16x8*>(&As[wr * 64 + mi * 16 + row][kk8]);
    #pragma unroll
    for (int ni = 0; ni < 4; ++ni)
      bfr[ni] = *reinterpret_cast<const bf16x8*>(&Bs[wc * 64 + ni * 16 + row][kk8]);
    #pragma unroll
    for (int mi = 0; mi < 4; ++mi)
      #pragma unroll
      for (int ni = 0; ni < 4; ++ni)
        acc[mi][ni] = __builtin_amdgcn_mfma_f32_16x16x32_bf16(af[mi], bfr[ni], acc[mi][ni], 0, 0, 0);
    __syncthreads();
  }
  u16* outb = (u16*)Cout;
  float* outf = (float*)Cout;
  #pragma unroll
  for (int mi = 0; mi < 4; ++mi) {
    #pragma unroll
    for (int ni = 0; ni < 4; ++ni) {
      int orow = m0 + wr * 64 + mi * 16 + ((lane >> 4) << 2);
      int ocol = n0 + wc * 64 + ni * 16 + (lane & 15);
      float bv = 0.0f;
      if constexpr (MODE != 0) bv = bias[ocol];
      #pragma unroll
      for (int r = 0; r < 4; ++r) {
        size_t off = (size_t)(orow + r) * N + ocol;
        float val = acc[mi][ni][r] + bv;
        if constexpr (MODE == 0) outb[off] = f2bf(val);
        else if constexpr (MODE == 1) outf[off] = val + resid[off];
        else if constexpr (MODE == 2) {
          outb[off] = f2bf(gelu_f(val));
        } else outf[off] = val;
      }
    }
  }
}

// ---------------------------------------------------------------- attention v3 (unchanged)
__global__ __launch_bounds__(512)
void attn_kernel(const u16* __restrict__ qg, const u16* __restrict__ kg,
                 const u16* __restrict__ vt, u16* __restrict__ og) {
  const int bh = blockIdx.y;
  const int q0 = blockIdx.x * 128;
  const int b = bh >> 4;
  const int tid = threadIdx.x, lane = tid & 63, w = tid >> 6;
  const int fr = lane & 15, kk8 = (lane >> 4) * 8;
  __shared__ u16 KS[2][4096];
  __shared__ u16 VS[2][4096];
  __shared__ u16 Ps[8][16][72];

  const int ldq = 2 * C_;
  const size_t baseq = ((size_t)b * T_) * ldq + (bh & 15) * HD_;
  const u16* qbase = qg + baseq;
  const u16* kbase = kg + baseq;
  const u16* vbase = vt + ((size_t)bh * HD_) * T_;
  const size_t baseo = ((size_t)b * T_) * C_ + (bh & 15) * HD_;
  const int qw = q0 + w * 16;

  bf16x8 qf[2];
  #pragma unroll
  for (int s = 0; s < 2; ++s)
    qf[s] = *reinterpret_cast<const bf16x8*>(&qbase[(size_t)(qw + fr) * ldq + s * 32 + kk8]);

  const int srow8 = lane >> 3;
  const int scol = 8 * ((lane & 7) ^ srow8);
  auto stageKV = [&](int d, int kv0) {
    int rr = w * 8 + srow8;
    gload16(kbase + (size_t)(kv0 + rr) * ldq + scol, &KS[d][w * 512]);
    gload16(vbase + (size_t)rr * T_ + kv0 + scol,    &VS[d][w * 512]);
  };
  auto ldS = [&](const u16* base, int row, int cu) -> bf16x8 {
    return *reinterpret_cast<const bf16x8*>(&base[row * 64 + (cu ^ ((row & 7) << 3))]);
  };

  f32x4 acc_o[4];
  #pragma unroll
  for (int dt = 0; dt < 4; ++dt) acc_o[dt] = (f32x4)0.0f;
  float m_run[4] = {-1e30f, -1e30f, -1e30f, -1e30f};
  float l_run[4] = {0.f, 0.f, 0.f, 0.f};
  const float scale = 0.125f;

  const int kv_end = q0 + 128;
  stageKV(0, 0);
  VMW(0); BAR();

  int cur = 0;
  for (int kv0 = 0; kv0 < kv_end; kv0 += 64, cur ^= 1) {
    if (kv0 + 64 < kv_end) stageKV(cur ^ 1, kv0 + 64);

    f32x4 sacc[4];
    #pragma unroll
    for (int nt = 0; nt < 4; ++nt) sacc[nt] = (f32x4)0.0f;
    #pragma unroll
    for (int nt = 0; nt < 4; ++nt)
      #pragma unroll
      for (int s = 0; s < 2; ++s) {
        bf16x8 kf = ldS(KS[cur], nt * 16 + fr, s * 32 + kk8);
        sacc[nt] = __builtin_amdgcn_mfma_f32_16x16x32_bf16(qf[s], kf, sacc[nt], 0, 0, 0);
      }

    #pragma unroll
    for (int i = 0; i < 4; ++i) {
      int qrow = qw + ((lane >> 4) << 2) + i;
      float sv[4], pv[4];
      #pragma unroll
      for (int nt = 0; nt < 4; ++nt) {
        sv[nt] = sacc[nt][i] * scale;
        if (kv0 + nt * 16 + (lane & 15) > qrow) sv[nt] = -1e30f;
      }
      float mx = fmaxf(fmaxf(sv[0], sv[1]), fmaxf(sv[2], sv[3]));
      #pragma unroll
      for (int d = 1; d < 16; d <<= 1) mx = fmaxf(mx, __shfl_xor(mx, d, 64));
      float mnew = fmaxf(m_run[i], mx);
      float rsum = 0.0f;
      #pragma unroll
      for (int nt = 0; nt < 4; ++nt) { pv[nt] = __expf(sv[nt] - mnew); rsum += pv[nt]; }
      float alpha = __expf(m_run[i] - mnew);
      #pragma unroll
      for (int d = 1; d < 16; d <<= 1) rsum += __shfl_xor(rsum, d, 64);
      l_run[i] = l_run[i] * alpha + rsum;
      m_run[i] = mnew;
      #pragma unroll
      for (int dt = 0; dt < 4; ++dt) acc_o[dt][i] *= alpha;
      #pragma unroll
      for (int nt = 0; nt < 4; ++nt)
        Ps[w][((lane >> 4) << 2) + i][(lane & 15) + nt * 16] = f2bf(pv[nt]);
    }

    #pragma unroll
    for (int dt = 0; dt < 4; ++dt)
      #pragma unroll
      for (int s = 0; s < 2; ++s) {
        bf16x8 pf = *reinterpret_cast<const bf16x8*>(&Ps[w][fr][s * 32 + kk8]);
        bf16x8 vf = ldS(VS[cur], dt * 16 + fr, s * 32 + kk8);
        acc_o[dt] = __builtin_amdgcn_mfma_f32_16x16x32_bf16(pf, vf, acc_o[dt], 0, 0, 0);
      }
    VMW(0); BAR();
  }

  #pragma unroll
  for (int dt = 0; dt < 4; ++dt)
    #pragma unroll
    for (int i = 0; i < 4; ++i) {
      int r = qw + ((lane >> 4) << 2) + i;
      float val = acc_o[dt][i] / l_run[i];
      og[baseo + (size_t)r * C_ + dt * 16 + (lane & 15)] = f2bf(val);
    }
}

// ---------------------------------------------------------------- attention legacy (fallback path)
__global__ __launch_bounds__(256)
void attn_legacy(const u16* __restrict__ qg, const u16* __restrict__ kg,
                 const u16* __restrict__ vg, u16* __restrict__ og, int ldq) {
  const int bh = blockIdx.y;
  const int b = bh >> 4, hh = bh & 15;
  const int q0 = blockIdx.x * 64;
  const int tid = threadIdx.x, lane = tid & 63, w = tid >> 6;
  const int row = lane & 15, kk8 = (lane >> 4) * 8;
  __shared__ u16 Ks[64][72];
  __shared__ u16 Vt[64][72];
  __shared__ u16 Ps[4][16][72];

  const size_t basei = ((size_t)b * T_) * ldq + hh * HD_;
  const size_t baseo = ((size_t)b * T_) * C_ + hh * HD_;
  const int qw = q0 + w * 16;

  bf16x8 qf[2];
  #pragma unroll
  for (int s = 0; s < 2; ++s)
    qf[s] = *reinterpret_cast<const bf16x8*>(&qg[basei + (size_t)(qw + row) * ldq + s * 32 + kk8]);

  f32x4 acc_o[4];
  #pragma unroll
  for (int dt = 0; dt < 4; ++dt) acc_o[dt] = (f32x4)0.0f;
  float m_run[4] = {-1e30f, -1e30f, -1e30f, -1e30f};
  float l_run[4] = {0.f, 0.f, 0.f, 0.f};
  const float scale = 0.125f;

  const int sc = (tid & 7) * 8;
  const int kv_end = q0 + 64;
  for (int kv0 = 0; kv0 < kv_end; kv0 += 64) {
    #pragma unroll
    for (int p = 0; p < 2; ++p) {
      int sr = p * 32 + (tid >> 3);
      *reinterpret_cast<uint4*>(&Ks[sr][sc]) =
        *reinterpret_cast<const uint4*>(&kg[basei + (size_t)(kv0 + sr) * ldq + sc]);
      union { uint4 u4; u16 us[8]; } vv;
      vv.u4 = *reinterpret_cast<const uint4*>(&vg[basei + (size_t)(kv0 + sr) * ldq + sc]);
      #pragma unroll
      for (int j = 0; j < 8; ++j) Vt[sc + j][sr] = vv.us[j];
    }
    __syncthreads();

    f32x4 sacc[4];
    #pragma unroll
    for (int nt = 0; nt < 4; ++nt) sacc[nt] = (f32x4)0.0f;
    #pragma unroll
    for (int nt = 0; nt < 4; ++nt)
      #pragma unroll
      for (int s = 0; s < 2; ++s) {
        bf16x8 kf = *reinterpret_cast<const bf16x8*>(&Ks[nt * 16 + row][s * 32 + kk8]);
        sacc[nt] = __builtin_amdgcn_mfma_f32_16x16x32_bf16(qf[s], kf, sacc[nt], 0, 0, 0);
      }

    #pragma unroll
    for (int i = 0; i < 4; ++i) {
      int qrow = qw + ((lane >> 4) << 2) + i;
      float sv[4], pv[4];
      #pragma unroll
      for (int nt = 0; nt < 4; ++nt) {
        sv[nt] = sacc[nt][i] * scale;
        if (kv0 + nt * 16 + (lane & 15) > qrow) sv[nt] = -1e30f;
      }
      float mx = fmaxf(fmaxf(sv[0], sv[1]), fmaxf(sv[2], sv[3]));
      #pragma unroll
      for (int d = 1; d < 16; d <<= 1) mx = fmaxf(mx, __shfl_xor(mx, d, 64));
      float mnew = fmaxf(m_run[i], mx);
      float rsum = 0.0f;
      #pragma unroll
      for (int nt = 0; nt < 4; ++nt) { pv[nt] = __expf(sv[nt] - mnew); rsum += pv[nt]; }
      float alpha = __expf(m_run[i] - mnew);
      #pragma unroll
      for (int d = 1; d < 16; d <<= 1) rsum += __shfl_xor(rsum, d, 64);
      l_run[i] = l_run[i] * alpha + rsum;
      m_run[i] = mnew;
      #pragma unroll
      for (int nt = 0; nt < 4; ++nt)
        Ps[w][((lane >> 4) << 2) + i][(lane & 15) + nt * 16] = f2bf(pv[nt]);
      #pragma unroll
      for (int dt = 0; dt < 4; ++dt) acc_o[dt][i] *= alpha;
    }

    #pragma unroll
    for (int dt = 0; dt < 4; ++dt)
      #pragma unroll
      for (int s = 0; s < 2; ++s) {
        bf16x8 pf = *reinterpret_cast<const bf16x8*>(&Ps[w][row][s * 32 + kk8]);
        bf16x8 vf = *reinterpret_cast<const bf16x8*>(&Vt[dt * 16 + row][s * 32 + kk8]);
        acc_o[dt] = __builtin_amdgcn_mfma_f32_16x16x32_bf16(pf, vf, acc_o[dt], 0, 0, 0);
      }
    __syncthreads();
  }

  #pragma unroll
  for (int dt = 0; dt < 4; ++dt)
    #pragma unroll
    for (int i = 0; i < 4; ++i) {
      int r = qw + ((lane >> 4) << 2) + i;
      float val = acc_o[dt][i] / l_run[i];
      og[baseo + (size_t)r * C_ + dt * 16 + (lane & 15)] = f2bf(val);
    }
}

// ---------------------------------------------------------------- launch
extern "C" void kernel_launch(void* const* d_in, const int* in_sizes, int n_in,
                              void* d_out, int out_size, void* d_ws, size_t ws_size,
                              hipStream_t stream) {
  const int*   idx  = (const int*)d_in[0];
  const float* emb  = (const float*)d_in[1];
  const float* pos  = (const float*)d_in[2];
  const float* Wq   = (const float*)d_in[3];
  const float* Wk   = (const float*)d_in[4];
  const float* Wv   = (const float*)d_in[5];
  const float* Wo   = (const float*)d_in[6];
  const float* bo   = (const float*)d_in[7];
  const float* W1   = (const float*)d_in[8];
  const float* b1   = (const float*)d_in[9];
  const float* W2   = (const float*)d_in[10];
  const float* b2   = (const float*)d_in[11];
  const float* ln1g = (const float*)d_in[12];
  const float* ln1b = (const float*)d_in[13];
  const float* ln2g = (const float*)d_in[14];
  const float* ln2b = (const float*)d_in[15];
  const float* lnfg = (const float*)d_in[16];
  const float* lnfb = (const float*)d_in[17];
  const float* Wlm  = (const float*)d_in[18];
  const float* blm  = (const float*)d_in[19];

  char* ws = (char*)d_ws;
  float* x    = (float*)ws;                             // 16 MiB
  u16*   h    = (u16*)(ws + (16u << 20));               //  8 MiB
  u16*   qkv  = (u16*)(ws + (24u << 20));               // 16 MiB [M][2C] (Q,K)
  u16*   vtb  = (u16*)(ws + (40u << 20));               //  8 MiB [B][H][64][T]
  u16*   ob   = (u16*)(ws + (48u << 20));               //  8 MiB
  u16*   ffb  = (u16*)(ws + (24u << 20));               // 32 MiB alias qkv+vtb+ob (dead)

  u16* WqkvT = (u16*)(ws + (56u  << 20));               // 24 MiB (L*3C*C)
  u16* WoT   = (u16*)(ws + (80u  << 20));               //  8 MiB
  u16* W1T   = (u16*)(ws + (88u  << 20));               // 32 MiB (L*FF*C)
  u16* W2T   = (u16*)(ws + (120u << 20));               // 32 MiB (L*C*FF)
  u16* WlmT  = (u16*)(ws + (152u << 20));               // 62.5 MiB (V*C)
  const size_t WS_NEED = (152ull << 20) + 2ull * C_ * V_;

  dim3 blk(256), blk8(512), blkA(512);
  const int nQKV  = (M_ / 128) * (3 * C_ / 128);  // 768
  const int nCC   = (M_ / 128) * (C_ / 128);      // 256
  const int nF1_8 = (M_ / 256) * (FF_ / 256);     // 256
  const int nLM_8 = (M_ / 256) * (V_ / 256);      // 2000
  dim3 gA(T_ / 128, B_ * H_);                     // 8 x 64

  if (ws_size >= WS_NEED) {
    const size_t s3 = (size_t)3 * C_ * C_;
    embed_kernel<1><<<M_, blk, 0, stream>>>(idx, emb, pos, x, ln1g, ln1b, h);
    wtrans4_kernel<<<dim3(C_ / 32, C_ / 32, 16), blk, 0, stream>>>(Wq, Wk, Wv, Wo, WqkvT, WoT);
    wtrans_kernel<<<dim3(FF_ / 32, C_ / 32, L_), blk, 0, stream>>>(W1, W1T, C_, FF_, (size_t)C_ * FF_);
    wtrans_kernel<<<dim3(C_ / 32, FF_ / 32, L_), blk, 0, stream>>>(W2, W2T, FF_, C_, (size_t)C_ * FF_);
    wtrans_kernel<<<dim3(V_ / 32,  C_ / 32, 1),  blk, 0, stream>>>(Wlm, WlmT, C_, V_, (size_t)C_ * V_);

    for (int l = 0; l < L_; ++l) {
      if (l > 0)
        ln_kernel<<<M_ / 4, blk, 0, stream>>>(x, ln1g + l * C_, ln1b + l * C_, h);
      gemm_bt<4, 8><<<nQKV, blk, 0, stream>>>(h, WqkvT + (size_t)l * s3, nullptr, nullptr, qkv, vtb, M_, 3 * C_, C_);
      attn_kernel<<<gA, blkA, 0, stream>>>(qkv, qkv + C_, vtb, ob);
      gemm_bt<1, 8><<<nCC, blk, 0, stream>>>(ob, WoT + (size_t)l * C_ * C_, bo + l * C_, x, x, nullptr, M_, C_, C_);
      ln_kernel<<<M_ / 4, blk, 0, stream>>>(x, ln2g + l * C_, ln2b + l * C_, h);
      gemm8<2><<<nF1_8, blk8, 0, stream>>>(h, W1T + (size_t)l * C_ * FF_, b1 + l * FF_, nullptr, ffb, M_, FF_, C_);
      gemm_bt<1, 8><<<nCC, blk, 0, stream>>>(ffb, W2T + (size_t)l * C_ * FF_, b2 + l * C_, x, x, nullptr, M_, C_, FF_);
    }
    ln_kernel<<<M_ / 4, blk, 0, stream>>>(x, lnfg, lnfb, h);
    gemm8<3><<<nLM_8, blk8, 0, stream>>>(h, WlmT, blm, nullptr, (float*)d_out, M_, V_, C_);
  } else {
    embed_kernel<0><<<M_, blk, 0, stream>>>(idx, emb, pos, x, nullptr, nullptr, nullptr);
    float* xr = x;
    u16* qb = qkv;
    u16* kb = qkv + (size_t)M_ * C_;
    u16* vb = (u16*)(ws + (40u << 20));
    dim3 gC(C_ / 128, M_ / 128);
    dim3 gF(FF_ / 128, M_ / 128);
    dim3 gV(V_ / 128, M_ / 128);
    dim3 gAl(T_ / 64, B_ * H_);
    for (int l = 0; l < L_; ++l) {
      ln_kernel<<<M_ / 4, blk, 0, stream>>>(xr, ln1g + l * C_, ln1b + l * C_, h);
      gemm_legacy<0><<<gC, blk, 0, stream>>>(h, Wq + (size_t)l * C_ * C_, nullptr, nullptr, qb, M_, C_, C_);
      gemm_legacy<0><<<gC, blk, 0, stream>>>(h, Wk + (size_t)l * C_ * C_, nullptr, nullptr, kb, M_, C_, C_);
      gemm_legacy<0><<<gC, blk, 0, stream>>>(h, Wv + (size_t)l * C_ * C_, nullptr, nullptr, vb, M_, C_, C_);
      attn_legacy<<<gAl, blk, 0, stream>>>(qb, kb, vb, ob, C_);
      gemm_legacy<1><<<gC, blk, 0, stream>>>(ob, Wo + (size_t)l * C_ * C_, bo + l * C_, xr, xr, M_, C_, C_);
      ln_kernel<<<M_ / 4, blk, 0, stream>>>(xr, ln2g + l * C_, ln2b + l * C_, h);
      gemm_legacy<2><<<gF, blk, 0, stream>>>(h, W1 + (size_t)l * C_ * FF_, b1 + l * FF_, nullptr, ffb, M_, FF_, C_);
      gemm_legacy<1><<<gC, blk, 0, stream>>>(ffb, W2 + (size_t)l * FF_ * C_, b2 + l * C_, xr, xr, M_, C_, FF_);
    }
    ln_kernel<<<M_ / 4, blk, 0, stream>>>(xr, lnfg, lnfb, h);
    gemm_legacy<3><<<gV, blk, 0, stream>>>(h, Wlm, blm, nullptr, (float*)d_out, M_, V_, C_);
  }
}